// Round 1
// baseline (209.631 us; speedup 1.0000x reference)
//
#include <hip/hip_runtime.h>

// NIGnet: X -> 64x [Y = X@W.T + b; X = (tanh(Y)+Y)/2] -> X@fW.T -> L2 normalize rows.
// Compute-bound: 2 tanh per point per layer => 128 v_exp + 128 v_rcp per point.
// tanh fused into the residual update:
//   t = 1 - 2*r, r = 1/(exp(2y)+1)  =>  x' = (y + t)/2 = 0.5*y + 0.5 - r
// Handles saturation exactly: y->+inf => r->0 => x'=(y+1)/2; y->-inf => r->1 => x'=(y-1)/2.

#define KPT 8          // points per thread (4 float4 loads) — ILP for trans latency
#define BLOCK 256

__global__ __launch_bounds__(BLOCK) void nig_kernel(
    const float* __restrict__ X_in,
    const float* __restrict__ Ws,    // [L,2,2] row-major
    const float* __restrict__ bs,    // [L,2]
    const float* __restrict__ fW,    // [2,2]
    float* __restrict__ out,
    int M,                           // number of float4 chunks (= N/2)
    int L)
{
    const int tid = blockIdx.x * blockDim.x + threadIdx.x;
    const int nthreads = gridDim.x * blockDim.x;

    const float4* __restrict__ in4 = (const float4*)X_in;
    float4* __restrict__ out4 = (float4*)out;

    float x0[KPT], x1[KPT];
    int idx4[KPT / 2];
    bool ok[KPT / 2];

    #pragma unroll
    for (int j = 0; j < KPT / 2; ++j) {
        idx4[j] = tid + j * nthreads;
        ok[j] = idx4[j] < M;
        float4 v = ok[j] ? in4[idx4[j]] : make_float4(0.f, 0.f, 0.f, 0.f);
        x0[2 * j]     = v.x; x1[2 * j]     = v.y;
        x0[2 * j + 1] = v.z; x1[2 * j + 1] = v.w;
    }

    const float C = 2.8853900817779268f;  // 2 * log2(e)

    for (int l = 0; l < L; ++l) {
        // Uniform addresses -> scalar loads through the constant cache.
        const float4 w = ((const float4*)Ws)[l];   // w00 w01 w10 w11
        const float2 b = ((const float2*)bs)[l];
        #pragma unroll
        for (int k = 0; k < KPT; ++k) {
            float y0 = fmaf(w.x, x0[k], fmaf(w.y, x1[k], b.x));
            float y1 = fmaf(w.z, x0[k], fmaf(w.w, x1[k], b.y));
            float e0 = __builtin_amdgcn_exp2f(y0 * C);
            float e1 = __builtin_amdgcn_exp2f(y1 * C);
            float r0 = __builtin_amdgcn_rcpf(e0 + 1.0f);
            float r1 = __builtin_amdgcn_rcpf(e1 + 1.0f);
            x0[k] = fmaf(0.5f, y0, 0.5f) - r0;
            x1[k] = fmaf(0.5f, y1, 0.5f) - r1;
        }
    }

    const float fw0 = fW[0], fw1 = fW[1], fw2 = fW[2], fw3 = fW[3];

    #pragma unroll
    for (int j = 0; j < KPT / 2; ++j) {
        if (!ok[j]) continue;
        float4 v;
        #pragma unroll
        for (int h = 0; h < 2; ++h) {
            const int k = 2 * j + h;
            float z0 = fmaf(fw0, x0[k], fw1 * x1[k]);
            float z1 = fmaf(fw2, x0[k], fw3 * x1[k]);
            float s  = fmaf(z0, z0, z1 * z1);
            float n  = __builtin_amdgcn_sqrtf(s);
            float inv = __builtin_amdgcn_rcpf(fmaxf(n, 1e-12f));
            float o0 = z0 * inv, o1 = z1 * inv;
            if (h == 0) { v.x = o0; v.y = o1; }
            else        { v.z = o0; v.w = o1; }
        }
        out4[idx4[j]] = v;
    }
}

extern "C" void kernel_launch(void* const* d_in, const int* in_sizes, int n_in,
                              void* d_out, int out_size, void* d_ws, size_t ws_size,
                              hipStream_t stream) {
    // inputs: 0=T(unused), 1=closed_manifold [N,2], 2=Ws [L,2,2], 3=bs [L,2], 4=final_W [2,2]
    const float* X  = (const float*)d_in[1];
    const float* Ws = (const float*)d_in[2];
    const float* bs = (const float*)d_in[3];
    const float* fW = (const float*)d_in[4];
    float* out = (float*)d_out;

    const int L = in_sizes[2] / 4;
    const int M = in_sizes[1] / 4;                 // float4 chunks (2 points each)
    const int threads = (M + (KPT / 2) - 1) / (KPT / 2);
    const int grid = (threads + BLOCK - 1) / BLOCK;

    nig_kernel<<<grid, BLOCK, 0, stream>>>(X, Ws, bs, fW, out, M, L);
}